// Round 1
// 270.364 us; speedup vs baseline: 1.0969x; 1.0969x over previous
//
#include <hip/hip_runtime.h>
#include <hip/hip_bf16.h>

#define NEG_SLOPE 0.2f
#define BSHIFT 9                 // 512 dsts per bucket
#define BSIZE  (1 << BSHIFT)
#define CAP    20480             // pairs capacity per bucket (mean ~16384, +32 sigma)
#define SRC_MASK 0x1FFFF         // 17 bits for src id (n < 131072)

__device__ __forceinline__ float lrelu(float x) { return fmaxf(x, NEG_SLOPE * x); }
__device__ __forceinline__ float bf2f(unsigned short u) {
    return __uint_as_float((unsigned)u << 16);
}
__device__ __forceinline__ unsigned short f2bf(float f) {
    unsigned u = __float_as_uint(f);
    return (unsigned short)((u + 0x7fffu + ((u >> 16) & 1u)) >> 16);  // RNE
}

// Pass 1: h = A @ W (wave per row) -> h16 (bf16), fused s_i = h.a_i, s_j = h.a_j
__global__ __launch_bounds__(256) void k_gemm(
    const float* __restrict__ A, const float* __restrict__ W,
    const float* __restrict__ att,
    unsigned short* __restrict__ h16, float* __restrict__ s_i, float* __restrict__ s_j, int n)
{
    __shared__ float Wl[64 * 64];
    __shared__ float Al[4][64];
    int tid = threadIdx.x;
    for (int t = tid; t < 64 * 64; t += 256) Wl[t] = W[t];
    int wave = tid >> 6, lane = tid & 63;
    int row = blockIdx.x * 4 + wave;
    float a_val = 0.f;
    if (row < n) a_val = A[(long)row * 64 + lane];
    Al[wave][lane] = a_val;
    __syncthreads();
    if (row >= n) return;

    float acc = 0.f;
#pragma unroll
    for (int k = 0; k < 64; ++k)
        acc = fmaf(Al[wave][k], Wl[k * 64 + lane], acc);

    // bf16 (RNE) copy of h for the gather pass
    h16[(long)row * 64 + lane] = f2bf(acc);

    float vi = acc * att[lane];
    float vj = acc * att[64 + lane];
#pragma unroll
    for (int off = 32; off; off >>= 1) {
        vi += __shfl_xor(vi, off, 64);
        vj += __shfl_xor(vj, off, 64);
    }
    if (lane == 0) { s_i[row] = vi; s_j[row] = vj; }
}

// Bin step A: count per bucket in LDS, reserve global bucket space, emit packed pairs.
__global__ __launch_bounds__(256) void k_binA(
    const int* __restrict__ edges, int* __restrict__ bcursor,
    unsigned* __restrict__ pairs, int n_edges, int nb)
{
    __shared__ int hist[256];
    __shared__ int cur[256];
    int t = threadIdx.x;
    hist[t] = 0;
    __syncthreads();
    long base = (long)blockIdx.x * 8192;

    for (int k = 0; k < 32; ++k) {
        long e = base + k * 256 + t;
        if (e < n_edges) {
            int d = edges[e];
            int i = (int)(e >> 5);
            if (d != i) atomicAdd(&hist[d >> BSHIFT], 1);
        }
    }
    __syncthreads();

    if (t < nb) {
        int c = hist[t];
        int g = 0;
        if (c) g = atomicAdd(&bcursor[t], c);
        cur[t] = t * CAP + g;
    }
    __syncthreads();

    for (int k = 0; k < 32; ++k) {
        long e = base + k * 256 + t;
        if (e < n_edges) {
            int d = edges[e];
            int i = (int)(e >> 5);
            if (d != i) {
                int b = d >> BSHIFT;
                int slot = atomicAdd(&cur[b], 1);
                if (slot < (b + 1) * CAP)
                    pairs[slot] = ((unsigned)(d & (BSIZE - 1)) << 17) | (unsigned)i;
            }
        }
    }
}

// Bin step B: one block per bucket. Stage pairs in LDS, per-dst hist+scan,
// write offs/counts, scatter src ids in-place into the srcl window.
__global__ __launch_bounds__(512) void k_binB(
    const int* __restrict__ bcursor, unsigned* __restrict__ pairs,
    int* __restrict__ offs, int* __restrict__ counts, int n)
{
    __shared__ unsigned pl[CAP];         // 80 KB
    __shared__ int hist[512];
    __shared__ int scn[512];
    __shared__ int cur[512];
    int b = blockIdx.x, t = threadIdx.x;
    int cnt = bcursor[b];
    if (cnt > CAP) cnt = CAP;
    long wb = (long)b * CAP;

    for (int s = t; s < cnt; s += 512) pl[s] = pairs[wb + s];
    hist[t] = 0;
    __syncthreads();
    for (int s = t; s < cnt; s += 512) atomicAdd(&hist[pl[s] >> 17], 1);
    __syncthreads();

    scn[t] = hist[t];
    __syncthreads();
    for (int d = 1; d < 512; d <<= 1) {
        int v = (t >= d) ? scn[t - d] : 0;
        __syncthreads();
        scn[t] += v;
        __syncthreads();
    }
    int start = scn[t] - hist[t];
    int dg = (b << BSHIFT) + t;
    if (dg < n) {
        offs[dg] = (int)(wb + start);
        counts[dg] = hist[t];
    }
    cur[t] = start;
    __syncthreads();

    for (int s = t; s < cnt; s += 512) {
        unsigned pk = pl[s];
        int dl = pk >> 17;
        int pos = atomicAdd(&cur[dl], 1);
        ((int*)pairs)[wb + pos] = (int)(pk & SRC_MASK);
    }
}

// Gather: wave per dst, reshaped as 8 groups x 8 lanes.
// Each lane loads dwordx4 (8 bf16 dims) of one src row -> one wave-load
// covers 8 edges. Weights/offsets broadcast via 2 bpermutes per 8 edges.
// Invalid lanes carry w=0, so padded iterations are numerically inert
// (they read row 0 with zero weight) -- no tail code needed.
__global__ __launch_bounds__(256) void k_gather(
    const int* __restrict__ offs, const int* __restrict__ counts,
    const int* __restrict__ srcl, const unsigned short* __restrict__ h16,
    const float* __restrict__ s_i, const float* __restrict__ s_j,
    const float* __restrict__ bias, float* __restrict__ out, int n)
{
    int gw = (blockIdx.x * 256 + threadIdx.x) >> 6;
    int lane = threadIdx.x & 63;
    if (gw >= n) return;
    const int d = gw;
    const int off = offs[d], deg = counts[d];
    const float si = s_i[d];
    const float es = __expf(lrelu(si + s_j[d]));   // self-loop weight

    const int g  = lane >> 3;                      // group: which edge of 8
    const int li = lane & 7;                       // dims [li*8, li*8+8)
    const char* hb = (const char*)h16 + (li << 4); // +16B per lane-in-group

    float acc[8];
#pragma unroll
    for (int i = 0; i < 8; ++i) acc[i] = 0.f;
    float denp = 0.f;

    for (int base = 0; base < deg; base += 64) {
        int t = base + lane;
        int cnt = min(64, deg - base);
        int soff = 0; float w = 0.f;
        if (t < deg) {
            int s = srcl[off + t];
            soff = s << 7;                         // byte offset of row s
            w = __expf(lrelu(si + s_j[s]));
        }
        denp += w;
        // 16 edges per iteration: 4 bpermutes + 2 dwordx4 loads + 16 fma/lane
        for (int j = 0; j < cnt; j += 16) {
            int i0 = j + g, i1 = j + 8 + g;
            float w0 = __shfl(w, i0, 64);
            int   o0 = __shfl(soff, i0, 64);
            float w1 = __shfl(w, i1, 64);
            int   o1 = __shfl(soff, i1, 64);
            uint4 ha = *(const uint4*)(hb + o0);
            uint4 hc = *(const uint4*)(hb + o1);
            acc[0] = fmaf(__uint_as_float(ha.x << 16),          w0, acc[0]);
            acc[1] = fmaf(__uint_as_float(ha.x & 0xffff0000u),  w0, acc[1]);
            acc[2] = fmaf(__uint_as_float(ha.y << 16),          w0, acc[2]);
            acc[3] = fmaf(__uint_as_float(ha.y & 0xffff0000u),  w0, acc[3]);
            acc[4] = fmaf(__uint_as_float(ha.z << 16),          w0, acc[4]);
            acc[5] = fmaf(__uint_as_float(ha.z & 0xffff0000u),  w0, acc[5]);
            acc[6] = fmaf(__uint_as_float(ha.w << 16),          w0, acc[6]);
            acc[7] = fmaf(__uint_as_float(ha.w & 0xffff0000u),  w0, acc[7]);
            acc[0] = fmaf(__uint_as_float(hc.x << 16),          w1, acc[0]);
            acc[1] = fmaf(__uint_as_float(hc.x & 0xffff0000u),  w1, acc[1]);
            acc[2] = fmaf(__uint_as_float(hc.y << 16),          w1, acc[2]);
            acc[3] = fmaf(__uint_as_float(hc.y & 0xffff0000u),  w1, acc[3]);
            acc[4] = fmaf(__uint_as_float(hc.z << 16),          w1, acc[4]);
            acc[5] = fmaf(__uint_as_float(hc.z & 0xffff0000u),  w1, acc[5]);
            acc[6] = fmaf(__uint_as_float(hc.w << 16),          w1, acc[6]);
            acc[7] = fmaf(__uint_as_float(hc.w & 0xffff0000u),  w1, acc[7]);
        }
    }

    // reduce group partials: groups live in lane bits 3..5 -> xor 8,16,32
#pragma unroll
    for (int o = 8; o <= 32; o <<= 1) {
#pragma unroll
        for (int i = 0; i < 8; ++i)
            acc[i] += __shfl_xor(acc[i], o, 64);
    }
    // den partials over all 64 lanes
#pragma unroll
    for (int o = 32; o; o >>= 1) denp += __shfl_xor(denp, o, 64);

    // self loop + epilogue (all groups hold identical values from here on)
    uint4 hd = *(const uint4*)(hb + (d << 7));
    float den = denp + es + 1e-16f;
    float rden = 1.f / den;
    const float4* pb = (const float4*)(bias + (li << 3));
    float4 b0 = pb[0], b1 = pb[1];

    float v[8];
    v[0] = fmaf(__uint_as_float(hd.x << 16),         es, acc[0]) * rden + b0.x;
    v[1] = fmaf(__uint_as_float(hd.x & 0xffff0000u), es, acc[1]) * rden + b0.y;
    v[2] = fmaf(__uint_as_float(hd.y << 16),         es, acc[2]) * rden + b0.z;
    v[3] = fmaf(__uint_as_float(hd.y & 0xffff0000u), es, acc[3]) * rden + b0.w;
    v[4] = fmaf(__uint_as_float(hd.z << 16),         es, acc[4]) * rden + b1.x;
    v[5] = fmaf(__uint_as_float(hd.z & 0xffff0000u), es, acc[5]) * rden + b1.y;
    v[6] = fmaf(__uint_as_float(hd.w << 16),         es, acc[6]) * rden + b1.z;
    v[7] = fmaf(__uint_as_float(hd.w & 0xffff0000u), es, acc[7]) * rden + b1.w;

    float sq = 0.f;
#pragma unroll
    for (int i = 0; i < 8; ++i) sq = fmaf(v[i], v[i], sq);
#pragma unroll
    for (int o = 1; o <= 4; o <<= 1) sq += __shfl_xor(sq, o, 64);
    float rn = 1.f / fmaxf(sqrtf(sq), 1e-12f);

    if (g < 2) {   // groups 0/1 write dims [li*8+4g, li*8+4g+4) once each
        float4 ov;
        if (g == 0) ov = make_float4(v[0] * rn, v[1] * rn, v[2] * rn, v[3] * rn);
        else        ov = make_float4(v[4] * rn, v[5] * rn, v[6] * rn, v[7] * rn);
        *(float4*)(out + ((long)d << 6) + (li << 3) + (g << 2)) = ov;
    }
}

extern "C" void kernel_launch(void* const* d_in, const int* in_sizes, int n_in,
                              void* d_out, int out_size, void* d_ws, size_t ws_size,
                              hipStream_t stream)
{
    const float* A    = (const float*)d_in[0]; // all_embed (n,64) f32
    const float* W    = (const float*)d_in[1]; // (64,64) f32
    const float* att  = (const float*)d_in[2]; // (128,) f32
    const float* bias = (const float*)d_in[3]; // (64,) f32
    const int* edges  = (const int*)d_in[7];   // (n,32) int32

    int n = in_sizes[0] / 64;          // 100000
    int n_edges = in_sizes[7];         // n * 32
    int nb = (n + BSIZE - 1) >> BSHIFT; // 196 buckets

    // workspace layout
    unsigned short* h16 = (unsigned short*)d_ws;    // n*64 bf16
    float* s_i      = (float*)(h16 + (long)n * 64); // n
    float* s_j      = s_i + n;                      // n
    int* offs       = (int*)(s_j + n);              // n
    int* counts     = offs + n;                     // n
    int* bcursor    = counts + n;                   // 256
    unsigned* pairs = (unsigned*)(bcursor + 256);   // nb*CAP (aliased as srcl after binB)

    (void)hipMemsetAsync(bcursor, 0, 256 * sizeof(int), stream);

    int blocks_rows = (n + 3) / 4;
    k_gemm<<<blocks_rows, 256, 0, stream>>>(A, W, att, h16, s_i, s_j, n);

    int blocks_binA = (n_edges + 8191) / 8192;
    k_binA<<<blocks_binA, 256, 0, stream>>>(edges, bcursor, pairs, n_edges, nb);

    k_binB<<<nb, 512, 0, stream>>>(bcursor, pairs, offs, counts, n);

    int blocks_waves = ((long)n * 64 + 255) / 256;  // wave per dst
    k_gather<<<blocks_waves, 256, 0, stream>>>(offs, counts, (const int*)pairs, h16,
                                               s_i, s_j, bias, (float*)d_out, n);
}